// Round 5
// baseline (343.959 us; speedup 1.0000x reference)
//
#include <hip/hip_runtime.h>
#include <cstdint>

#define NPOS   32768   // B*H*W
#define KCODE  1024
#define DDIM   256

typedef unsigned long long u64;
typedef __attribute__((ext_vector_type(16))) float f32x16;

// wave-uniform scalar load: 16 dwords -> 16 SGPRs (one z-row slice = 16 n)
template<int OFF>
__device__ __forceinline__ f32x16 sload16(const float* p) {
  f32x16 r;
  asm volatile("s_load_dwordx16 %0, %1, %2" : "=s"(r) : "s"(p), "i"(OFF));
  return r;
}

// async global->LDS DMA, 16B per lane; LDS base wave-uniform, lane scatter i*16B
__device__ __forceinline__ void async_copy16(const float* g, float* lds) {
  __builtin_amdgcn_global_load_lds(
      (const __attribute__((address_space(1))) uint32_t*)g,
      (__attribute__((address_space(3))) uint32_t*)lds, 16, 0, 0);
}

__device__ __forceinline__ void fma4(float4& a, float s, const float4& b) {
  a.x = fmaf(s, b.x, a.x); a.y = fmaf(s, b.y, a.y);
  a.z = fmaf(s, b.z, a.z); a.w = fmaf(s, b.w, a.w);
}

// ---- kernel 0: wsq[k] = sum_d w[k][d]^2 ------------------------------------
__global__ void wsq_kernel(const float* __restrict__ w, float* __restrict__ wsq) {
  const int k = blockIdx.x;       // 1024
  const int lane = threadIdx.x;   // 64
  float4 v = *(const float4*)(w + (size_t)k * DDIM + lane * 4);
  float s = v.x * v.x + v.y * v.y + v.z * v.z + v.w * v.w;
  #pragma unroll
  for (int off = 32; off > 0; off >>= 1) s += __shfl_down(s, off, 64);
  if (lane == 0) wsq[k] = s;
}

// ---- kernel 0b: wt[d][k] = w[k][d], LDS-tiled transpose --------------------
__global__ void wt_kernel(const float* __restrict__ w, float* __restrict__ wt) {
  __shared__ float T[64][65];
  const int k0 = blockIdx.x * 64;   // 16
  const int d0 = blockIdx.y * 64;   // 4
  const int c = threadIdx.x & 63;
  const int r = threadIdx.x >> 6;   // 0..3
  #pragma unroll
  for (int p = 0; p < 16; ++p) {
    const int kk = p * 4 + r;
    T[kk][c] = w[(size_t)(k0 + kk) * DDIM + d0 + c];
  }
  __syncthreads();
  #pragma unroll
  for (int p = 0; p < 16; ++p) {
    const int dd = p * 4 + r;
    wt[(size_t)(d0 + dd) * KCODE + k0 + c] = T[c][dd];
  }
}

// ---- kernel 1: fused dist-GEMM + argmin ------------------------------------
// Block: 16 n, 256 threads (4 waves). Wave wv owns k-quarter [wv*256,+256);
// lane l covers k = wv*256 + l*4 .. +3 (one f4 acc per n). A (z-rows) arrives
// via s_load_dwordx16 (z native [d][hw] layout: 16 n at fixed d = 64B line),
// ping-ponged one d ahead. B streams global->LDS via async DMA, double-
// buffered 4-d chunks, one barrier per chunk. 4 blocks/CU -> barrier stalls
// of one block covered by the other three.
__global__ __launch_bounds__(256, 4) void argmin_kernel(
    const float* __restrict__ z, const float* __restrict__ wt,
    const float* __restrict__ wsq, int* __restrict__ idxout) {
  __shared__ __align__(16) float Bs[2][4 * KCODE];  // 32 KB
  __shared__ u64 Red[4][16];

  const int tid = threadIdx.x;
  const int l = tid & 63;
  const int wv = tid >> 6;          // 0..3 = k-quarter
  const int klq = wv * 256 + l * 4; // this lane's k base
  const int n0 = blockIdx.x * 16;   // 2048 blocks
  const int bimg = n0 >> 10;
  const int hw0 = n0 & 1023;
  const float* zb = z + (size_t)bimg * DDIM * 1024 + hw0;  // + d*1024 per row

  // DMA chunk 0 -> Bs[0]
  #pragma unroll
  for (int q = 0; q < 4; ++q)
    async_copy16(wt + q * 1024 + tid * 4, &Bs[0][0] + q * 1024 + wv * 256);

  f32x16 A0 = sload16<0>(zb);   // d = 0
  f32x16 A1;

  float4 acc[16];
  #pragma unroll
  for (int n = 0; n < 16; ++n) acc[n] = make_float4(0.f, 0.f, 0.f, 0.f);

  __syncthreads();   // drains chunk-0 DMA (and A0 issue is long since queued)

#define STEP(ACUR, ANEXT, DD, DPF)                                     \
  {                                                                    \
    float4 b = *(const float4*)(bs + (DD) * KCODE + klq);              \
    asm volatile("s_waitcnt lgkmcnt(0)" : "+s"(ACUR) :: "memory");     \
    ANEXT = sload16<0>(zb + (DPF) * 1024);                             \
    _Pragma("unroll")                                                  \
    for (int n = 0; n < 16; ++n) fma4(acc[n], ACUR[n], b);             \
  }

  #pragma unroll 2
  for (int dc = 0; dc < 64; ++dc) {
    // DMA chunk dc+1 into the other buffer (readers left it at last barrier)
    {
      const int nc = (dc + 1) & 63;
      float* bn = &Bs[(dc + 1) & 1][0];
      const float* gsrc = wt + (size_t)nc * 4096;
      #pragma unroll
      for (int q = 0; q < 4; ++q)
        async_copy16(gsrc + q * 1024 + tid * 4, bn + q * 1024 + wv * 256);
    }
    const float* bs = &Bs[dc & 1][0];
    const int d0 = dc * 4;
    STEP(A0, A1, 0, (d0 + 1) & 255);
    STEP(A1, A0, 1, (d0 + 2) & 255);
    STEP(A0, A1, 2, (d0 + 3) & 255);
    STEP(A1, A0, 3, (d0 + 4) & 255);
    __syncthreads();   // Bs[dc&1] free; own DMA (dc+1) drained (issued ~512 cyc ago)
  }
#undef STEP

  // ---- epilogue: dist = wsq[k] - 2*dot, packed-key argmin ----
  float4 wq = *(const float4*)(wsq + klq);
  u64 best[16];
  #pragma unroll
  for (int n = 0; n < 16; ++n) {
    const float dq[4] = {wq.x - 2.f * acc[n].x, wq.y - 2.f * acc[n].y,
                         wq.z - 2.f * acc[n].z, wq.w - 2.f * acc[n].w};
    u64 m = ~0ull;
    #pragma unroll
    for (int c = 0; c < 4; ++c) {
      unsigned u = __float_as_uint(dq[c]);
      u = (u & 0x80000000u) ? ~u : (u | 0x80000000u);  // monotone total order
      u64 key = ((u64)u << 32) | (unsigned)(klq + c);
      m = m < key ? m : key;   // ties -> smallest k
    }
    best[n] = m;
  }
  #pragma unroll
  for (int off = 1; off < 64; off <<= 1) {
    #pragma unroll
    for (int n = 0; n < 16; ++n) {
      u64 o = __shfl_xor((unsigned long long)best[n], off, 64);
      best[n] = o < best[n] ? o : best[n];
    }
  }
  if (l == 0) {
    #pragma unroll
    for (int n = 0; n < 16; ++n) Red[wv][n] = best[n];
  }
  __syncthreads();
  if (tid < 16) {
    u64 m = Red[0][tid];
    #pragma unroll
    for (int v2 = 1; v2 < 4; ++v2) {
      u64 o = Red[v2][tid];
      m = o < m ? o : m;
    }
    idxout[n0 + tid] = (int)(m & 0xFFFFFFFFull);
  }
}

// ---- kernel 2: gather via LDS-resident w-slice (reads wt) ------------------
#define WPITCH 1028
__global__ __launch_bounds__(256) void gather2_kernel(
    const float* __restrict__ wt, const int* __restrict__ idx,
    float* __restrict__ out) {
  __shared__ __align__(16) float Ws[16 * WPITCH];   // 65.8 KB
  const int tid = threadIdx.x;
  const int bimg = blockIdx.x >> 4;
  const int c0 = (blockIdx.x & 15) * 16;
  int4 kv = *(const int4*)(idx + bimg * 1024 + tid * 4);   // hw = tid*4..+3
  #pragma unroll
  for (int cc = 0; cc < 16; ++cc) {
    float4 v = *(const float4*)(wt + (size_t)(c0 + cc) * KCODE + tid * 4);
    *(float4*)(Ws + cc * WPITCH + tid * 4) = v;
  }
  __syncthreads();
  float* ob = out + (size_t)bimg * DDIM * 1024 + (size_t)c0 * 1024 + tid * 4;
  #pragma unroll
  for (int cc = 0; cc < 16; ++cc) {
    const float* wr = Ws + cc * WPITCH;
    float4 v;
    v.x = wr[kv.x]; v.y = wr[kv.y]; v.z = wr[kv.z]; v.w = wr[kv.w];
    *(float4*)(ob + (size_t)cc * 1024) = v;               // codes
    *(float4*)(ob + (size_t)cc * 1024 + 8388608) = v;     // codes_bar
  }
}

// fallback gather (no wt dependency) for tiny-workspace case
__global__ void gather_kernel(const float* __restrict__ w, const int* __restrict__ idx,
                              float* __restrict__ out) {
  const int g = blockIdx.x * 256 + threadIdx.x;
  const int hw4 = g & 255;
  const int c = (g >> 8) & 255;
  const int b = g >> 16;
  int4 kv = *(const int4*)(idx + b * 1024 + hw4 * 4);
  float4 v;
  v.x = w[(size_t)kv.x * 256 + c];
  v.y = w[(size_t)kv.y * 256 + c];
  v.z = w[(size_t)kv.z * 256 + c];
  v.w = w[(size_t)kv.w * 256 + c];
  float4* o = (float4*)out;
  o[g] = v;
  o[g + 2097152] = v;
}

extern "C" void kernel_launch(void* const* d_in, const int* in_sizes, int n_in,
                              void* d_out, int out_size, void* d_ws, size_t ws_size,
                              hipStream_t stream) {
  const float* z = (const float*)d_in[0];   // [32,256,32,32] fp32
  const float* w = (const float*)d_in[1];   // [1024,256] fp32
  float* out = (float*)d_out;

  float* wsq = (float*)d_ws;                 // 4 KB @ 0
  int* idx = (int*)((char*)d_ws + 4096);     // 128 KB @ 4 KB
  const size_t need = 4096 + 131072 + 1048576;
  const bool ws_ok = ws_size >= need;
  float* wt = ws_ok ? (float*)((char*)d_ws + 4096 + 131072)
                    : out + (size_t)out_size - 262144;

  wsq_kernel<<<KCODE, 64, 0, stream>>>(w, wsq);
  wt_kernel<<<dim3(16, 4), 256, 0, stream>>>(w, wt);
  argmin_kernel<<<NPOS / 16, 256, 0, stream>>>(z, wt, wsq, idx);
  if (ws_ok)
    gather2_kernel<<<512, 256, 0, stream>>>(wt, idx, out);
  else
    gather_kernel<<<2097152 / 256, 256, 0, stream>>>(w, idx, out);
}

// Round 6
// 181.906 us; speedup vs baseline: 1.8909x; 1.8909x over previous
//
#include <hip/hip_runtime.h>
#include <cstdint>

#define NPOS   32768   // B*H*W
#define KCODE  1024
#define DDIM   256

typedef unsigned long long u64;
typedef unsigned short u16;
typedef __attribute__((ext_vector_type(8))) short short8x;   // 8 bf16 (4 VGPR)
typedef __attribute__((ext_vector_type(4))) float f32x4;     // MFMA acc

__device__ __forceinline__ u16 bf16_rne(float x) {
  unsigned u = __float_as_uint(x);
  return (u16)((u + 0x7fffu + ((u >> 16) & 1u)) >> 16);
}
__device__ __forceinline__ float bf16_tof(u16 h) {
  return __uint_as_float(((unsigned)h) << 16);
}

// async global->LDS DMA, 16B/lane; LDS base wave-uniform, lane scatter i*16B
__device__ __forceinline__ void async_copy16(const float* g, float* lds) {
  __builtin_amdgcn_global_load_lds(
      (const __attribute__((address_space(1))) uint32_t*)g,
      (__attribute__((address_space(3))) uint32_t*)lds, 16, 0, 0);
}

// ---- kernel 0: per code K: wsq[K] AND Wp (virtual-K packed, quad-swizzled) -
// Virtual-K regions (24 chunks of 32 vd): vc 0..7 -> Wh (x Xh),
// vc 8..15 -> Wh (x Xl), vc 16..23 -> Wl (x Xh).
// Layout: Wp[kh][vc][k=K&511][quad'][8 e] bf16, quad' = quad ^ ((k>>2)&3).
__global__ void pack_w(const float* __restrict__ w, u16* __restrict__ Wp,
                       float* __restrict__ wsq) {
  const int K = blockIdx.x;        // 1024
  const int t = threadIdx.x;       // 64
  const int d0 = t * 4;
  float4 v = *(const float4*)(w + (size_t)K * DDIM + d0);
  float s = v.x * v.x + v.y * v.y + v.z * v.z + v.w * v.w;
  const float xs[4] = {v.x, v.y, v.z, v.w};
  u16 h[4], lo[4];
  #pragma unroll
  for (int i = 0; i < 4; ++i) {
    h[i] = bf16_rne(xs[i]);
    lo[i] = bf16_rne(xs[i] - bf16_tof(h[i]));
  }
  const int k = K & 511, kh = K >> 9;
  const int sw = (k >> 2) & 3;
  const int qp = ((d0 >> 3) & 3) ^ sw;
  const int e = d0 & 7;
  #pragma unroll
  for (int rb = 0; rb < 3; ++rb) {
    const int vc = rb * 8 + (d0 >> 5);
    const u16* src = (rb < 2) ? h : lo;
    size_t off = ((((size_t)(kh * 24 + vc)) * 512 + k) * 4 + qp) * 8 + e;
    *(ushort4*)(Wp + off) = make_ushort4(src[0], src[1], src[2], src[3]);
  }
  #pragma unroll
  for (int off = 32; off > 0; off >>= 1) s += __shfl_down(s, off, 64);
  if (t == 0) wsq[K] = s;
}

// ---- kernel 0b: wt[d][k] = w[k][d] (for gather2) ---------------------------
__global__ void wt_kernel(const float* __restrict__ w, float* __restrict__ wt) {
  __shared__ float T[64][65];
  const int k0 = blockIdx.x * 64;
  const int d0 = blockIdx.y * 64;
  const int c = threadIdx.x & 63;
  const int r = threadIdx.x >> 6;
  #pragma unroll
  for (int p = 0; p < 16; ++p)
    T[p * 4 + r][c] = w[(size_t)(k0 + p * 4 + r) * DDIM + d0 + c];
  __syncthreads();
  #pragma unroll
  for (int p = 0; p < 16; ++p)
    wt[(size_t)(d0 + p * 4 + r) * KCODE + k0 + c] = T[c][p * 4 + r];
}

// ---- kernel 1: MFMA dist-GEMM + argmin -------------------------------------
// Grid: 512 n-blocks x 2 k-halves. Block 256 thr (4 waves); wave wv owns codes
// [kh*512 + wv*128, +128) as 8 16x16 A-tiles x 4 n-tiles (64 n) = 128 AGPR.
// W: DMA'd 32-vd chunks (dbuf). X: z fp32 -> bf16 h/l converted on the fly.
__global__ __launch_bounds__(256, 2) void argmin_mfma(
    const float* __restrict__ z, const u16* __restrict__ Wp,
    const float* __restrict__ wsq, u64* __restrict__ part) {
  __shared__ __align__(16) u16 Ws[2][512 * 32];   // 64 KB
  __shared__ __align__(16) u16 Xs[2][64 * 32];    // 8 KB
  __shared__ u64 Red[4][64];

  const int tid = threadIdx.x;
  const int l = tid & 63, wv = tid >> 6;
  const int m = l & 15, g = l >> 4;
  const int nb = blockIdx.x >> 1, kh = blockIdx.x & 1;
  const int n0 = nb * 64;
  const int bimg = n0 >> 10, hw0 = n0 & 1023;
  const float* zb = z + (size_t)bimg * DDIM * 1024 + hw0;

  const int nz = l;                                // conversion row (n local)
  const int qxB = ((g ^ ((m >> 2) & 3)) * 16);     // swizzled quad, bytes
  const int aoff = (wv * 128 + m) * 64 + qxB;      // A-frag byte offset in Ws
  const int boff = m * 64 + qxB;                   // B-frag byte offset in Xs
  const int qzB = ((wv ^ ((nz >> 2) & 3)) * 16);   // conversion write quad

  const float* WpF = (const float*)(Wp + (size_t)kh * 24 * 16384);

  f32x4 acc[8][4];
  #pragma unroll
  for (int ct = 0; ct < 8; ++ct)
    #pragma unroll
    for (int nt = 0; nt < 4; ++nt) acc[ct][nt] = (f32x4){0.f, 0.f, 0.f, 0.f};

  float xv[8];
  // ---- prologue: stage chunk 0 (region h, d-base 0) ----
  {
    #pragma unroll
    for (int i = 0; i < 8; ++i)
      xv[i] = zb[(size_t)(wv * 8 + i) * 1024 + nz];
    #pragma unroll
    for (int j = 0; j < 8; ++j)
      async_copy16(WpF + j * 1024 + tid * 4, (float*)Ws[0] + j * 1024 + wv * 256);
    short8x xw;
    #pragma unroll
    for (int i = 0; i < 8; ++i) xw[i] = (short)bf16_rne(xv[i]);
    *(short8x*)((char*)Xs[0] + nz * 64 + qzB) = xw;
    __syncthreads();
  }

  #pragma unroll 1
  for (int c = 0; c < 24; ++c) {
    const int nc = (c + 1 < 24) ? c + 1 : 0;   // wrap: harmless reload
    // z loads for chunk nc (latency hidden under the mfma block)
    const int d0n = (nc & 7) * 32;
    #pragma unroll
    for (int i = 0; i < 8; ++i)
      xv[i] = zb[(size_t)(d0n + wv * 8 + i) * 1024 + nz];
    // DMA W chunk nc into the other buffer
    {
      const float* wsrc = WpF + (size_t)nc * 8192;
      float* ld = (float*)Ws[(c + 1) & 1];
      #pragma unroll
      for (int j = 0; j < 8; ++j)
        async_copy16(wsrc + j * 1024 + tid * 4, ld + j * 1024 + wv * 256);
    }
    // compute chunk c: 12 frag reads, 32 mfma
    {
      const char* wb = (const char*)Ws[c & 1];
      const char* xb = (const char*)Xs[c & 1];
      short8x af[8], bfr[4];
      #pragma unroll
      for (int ct = 0; ct < 8; ++ct)
        af[ct] = *(const short8x*)(wb + aoff + ct * 1024);
      #pragma unroll
      for (int nt = 0; nt < 4; ++nt)
        bfr[nt] = *(const short8x*)(xb + boff + nt * 1024);
      #pragma unroll
      for (int ct = 0; ct < 8; ++ct)
        #pragma unroll
        for (int nt = 0; nt < 4; ++nt)
          acc[ct][nt] = __builtin_amdgcn_mfma_f32_16x16x32_bf16(
              af[ct], bfr[nt], acc[ct][nt], 0, 0, 0);
    }
    // convert + write X chunk nc (other buffer; no race with readers of c)
    {
      const bool isl = ((nc >> 3) == 1);   // region 1 -> X = lo
      short8x xw;
      #pragma unroll
      for (int i = 0; i < 8; ++i) {
        u16 h = bf16_rne(xv[i]);
        u16 o = isl ? bf16_rne(xv[i] - bf16_tof(h)) : h;
        xw[i] = (short)o;
      }
      *(short8x*)((char*)Xs[(c + 1) & 1] + nz * 64 + qzB) = xw;
    }
    __syncthreads();
  }

  // ---- epilogue: dist = wsq[k] - 2*dot, packed-key argmin ----
  const int cbase = kh * 512 + wv * 128;
  float4 wq[8];
  #pragma unroll
  for (int ct = 0; ct < 8; ++ct)
    wq[ct] = *(const float4*)(wsq + cbase + ct * 16 + g * 4);

  #pragma unroll
  for (int nt = 0; nt < 4; ++nt) {
    u64 best = ~0ull;
    #pragma unroll
    for (int ct = 0; ct < 8; ++ct) {
      const float* wqv = (const float*)&wq[ct];
      #pragma unroll
      for (int r = 0; r < 4; ++r) {
        // C/D layout: row(code) = g*4 + r, col(n) = m   [m89-verified]
        float dist = wqv[r] - 2.0f * acc[ct][nt][r];
        unsigned u = __float_as_uint(dist);
        u = (u & 0x80000000u) ? ~u : (u | 0x80000000u);  // monotone order
        u64 key = ((u64)u << 32) | (unsigned)(cbase + ct * 16 + g * 4 + r);
        best = best < key ? best : key;                  // ties -> smallest k
      }
    }
    u64 o = __shfl_xor(best, 16, 64); best = o < best ? o : best;
    o = __shfl_xor(best, 32, 64);     best = o < best ? o : best;
    if (l < 16) Red[wv][nt * 16 + l] = best;   // n_local = nt*16 + m
  }
  __syncthreads();
  if (tid < 64) {
    u64 a0 = Red[0][tid], a1 = Red[1][tid];
    u64 a2 = Red[2][tid], a3 = Red[3][tid];
    u64 mA = a0 < a1 ? a0 : a1;
    u64 mB = a2 < a3 ? a2 : a3;
    mA = mA < mB ? mA : mB;
    part[(size_t)kh * NPOS + n0 + tid] = mA;
  }
}

// ---- kernel 1b: combine the two k-half partials ----------------------------
__global__ void combine_kernel(const u64* __restrict__ part, int* __restrict__ idx) {
  const int n = blockIdx.x * 256 + threadIdx.x;
  u64 a = part[n], b = part[NPOS + n];
  idx[n] = (int)((a < b ? a : b) & 0xffffffffull);
}

// ---- kernel 2: gather via LDS-resident w-slice (reads wt) ------------------
#define WPITCH 1028
__global__ __launch_bounds__(256) void gather2_kernel(
    const float* __restrict__ wt, const int* __restrict__ idx,
    float* __restrict__ out) {
  __shared__ __align__(16) float Ws[16 * WPITCH];
  const int tid = threadIdx.x;
  const int bimg = blockIdx.x >> 4;
  const int c0 = (blockIdx.x & 15) * 16;
  int4 kv = *(const int4*)(idx + bimg * 1024 + tid * 4);
  #pragma unroll
  for (int cc = 0; cc < 16; ++cc) {
    float4 v = *(const float4*)(wt + (size_t)(c0 + cc) * KCODE + tid * 4);
    *(float4*)(Ws + cc * WPITCH + tid * 4) = v;
  }
  __syncthreads();
  float* ob = out + (size_t)bimg * DDIM * 1024 + (size_t)c0 * 1024 + tid * 4;
  #pragma unroll
  for (int cc = 0; cc < 16; ++cc) {
    const float* wr = Ws + cc * WPITCH;
    float4 v;
    v.x = wr[kv.x]; v.y = wr[kv.y]; v.z = wr[kv.z]; v.w = wr[kv.w];
    *(float4*)(ob + (size_t)cc * 1024) = v;               // codes
    *(float4*)(ob + (size_t)cc * 1024 + 8388608) = v;     // codes_bar
  }
}

// fallback gather (no wt dependency)
__global__ void gather_kernel(const float* __restrict__ w, const int* __restrict__ idx,
                              float* __restrict__ out) {
  const int gi = blockIdx.x * 256 + threadIdx.x;
  const int hw4 = gi & 255;
  const int c = (gi >> 8) & 255;
  const int b = gi >> 16;
  int4 kv = *(const int4*)(idx + b * 1024 + hw4 * 4);
  float4 v;
  v.x = w[(size_t)kv.x * 256 + c];
  v.y = w[(size_t)kv.y * 256 + c];
  v.z = w[(size_t)kv.z * 256 + c];
  v.w = w[(size_t)kv.w * 256 + c];
  float4* o = (float4*)out;
  o[gi] = v;
  o[gi + 2097152] = v;
}

extern "C" void kernel_launch(void* const* d_in, const int* in_sizes, int n_in,
                              void* d_out, int out_size, void* d_ws, size_t ws_size,
                              hipStream_t stream) {
  const float* z = (const float*)d_in[0];   // [32,256,32,32] fp32
  const float* w = (const float*)d_in[1];   // [1024,256] fp32
  float* out = (float*)d_out;

  float* wsq = (float*)d_ws;                 // 4 KB @ 0
  int* idx = (int*)((char*)d_ws + 4096);     // 128 KB @ 4 KB
  const size_t need = 4096 + 131072 + 1048576;
  const bool ws_ok = ws_size >= need;
  float* wt = ws_ok ? (float*)((char*)d_ws + 4096 + 131072)
                    : out + (size_t)out_size - 262144;

  // Scratch in the codes_bar half of d_out (fully consumed before gather
  // overwrites it; stream-ordered): Wp 1.5 MB, partials 512 KB.
  u16* Wp   = (u16*)(out + 8388608);         // floats [8388608, 8781824)
  u64* part = (u64*)(out + 8781824);         // floats [8781824, 8912896)

  pack_w<<<KCODE, 64, 0, stream>>>(w, Wp, wsq);
  wt_kernel<<<dim3(16, 4), 256, 0, stream>>>(w, wt);
  argmin_mfma<<<1024, 256, 0, stream>>>(z, Wp, wsq, part);
  combine_kernel<<<NPOS / 256, 256, 0, stream>>>(part, idx);
  if (ws_ok)
    gather2_kernel<<<512, 256, 0, stream>>>(wt, idx, out);
  else
    gather_kernel<<<2097152 / 256, 256, 0, stream>>>(w, idx, out);
}